// Round 12
// baseline (168.758 us; speedup 1.0000x reference)
//
#include <hip/hip_runtime.h>

// ---------------------------------------------------------------------------
// AttentionWithLoRA, 4-kernel chain:
//   prep  (LN + WA=w_out@outA + beff + WqkvT fold z0-2)
//   gemm0 (QKV GEMM + WoutT fold tail)
//   attn  (flash attention; V read direct from L2, no V staging)
//   gemm1 (out-proj + bias)
// ---------------------------------------------------------------------------

#define DIMSZ 1024
#define TSEQ  2048
#define MTOK  4096   // B*T rows

typedef __attribute__((ext_vector_type(8))) short bf16x8;
typedef __attribute__((ext_vector_type(4))) short bf16x4;
typedef __attribute__((ext_vector_type(4))) float f32x4;

__device__ __forceinline__ unsigned short f2bf(float f) {
  unsigned int u = __float_as_uint(f);
  u += 0x7fffu + ((u >> 16) & 1u);   // round-nearest-even
  return (unsigned short)(u >> 16);
}
__device__ __forceinline__ float bf2f(unsigned short s) {
  return __uint_as_float(((unsigned int)s) << 16);
}
__device__ __forceinline__ unsigned int cvtpk_bf16(float a, float b) {
  unsigned int d;
  asm("v_cvt_pk_bf16_f32 %0, %1, %2" : "=v"(d) : "v"(a), "v"(b));
  return d;
}
__device__ __forceinline__ void gload16(const void* g, void* l) {
  __builtin_amdgcn_global_load_lds((const __attribute__((address_space(1))) void*)g,
                                   (__attribute__((address_space(3))) void*)l, 16, 0, 0);
}

// ---------------------------------------------------------------------------
// prep: blocks 0..4095 LayerNorm; 4096..4351 WA=w_out@outA (4 rows/blk);
// 4352: beff; 4353..5120: WqkvT fold (z = (bid-4353)>>8, 16x16 64-blocks).
// ---------------------------------------------------------------------------
__global__ __launch_bounds__(256) void prep_kernel(const float* __restrict__ x,
    const float* __restrict__ g, const float* __restrict__ bln,
    const float* __restrict__ w_out, const float* __restrict__ outA,
    const float* __restrict__ b_out, const float* __restrict__ outB,
    const float* __restrict__ w_qkv,
    const float* __restrict__ qA, const float* __restrict__ qB,
    const float* __restrict__ kA, const float* __restrict__ kB,
    const float* __restrict__ vA, const float* __restrict__ vB,
    unsigned short* __restrict__ xn, float* __restrict__ WA,
    float* __restrict__ beff, unsigned short* __restrict__ WqkvT) {
  __shared__ float red[8];
  __shared__ float sh[4][16];
  __shared__ float tt[16];
  int bid = blockIdx.x;
  int tid = threadIdx.x, wid = tid >> 6, lane = tid & 63;
  if (bid < MTOK) {
    int row = bid;
    const float4* xr = (const float4*)(x + (size_t)row * DIMSZ);
    float4 v = xr[tid];
    float s  = v.x + v.y + v.z + v.w;
    float s2 = v.x*v.x + v.y*v.y + v.z*v.z + v.w*v.w;
    #pragma unroll
    for (int off = 32; off > 0; off >>= 1) {
      s  += __shfl_xor(s, off, 64);
      s2 += __shfl_xor(s2, off, 64);
    }
    if (lane == 0) { red[wid] = s; red[wid + 4] = s2; }
    __syncthreads();
    s  = red[0] + red[1] + red[2] + red[3];
    s2 = red[4] + red[5] + red[6] + red[7];
    float mu  = s * (1.0f / DIMSZ);
    float var = s2 * (1.0f / DIMSZ) - mu * mu;
    float rstd = rsqrtf(var + 1e-5f);
    float4 gg = ((const float4*)g)[tid];
    float4 bb = ((const float4*)bln)[tid];
    ushort4 o;
    o.x = f2bf((v.x - mu) * rstd * gg.x + bb.x);
    o.y = f2bf((v.y - mu) * rstd * gg.y + bb.y);
    o.z = f2bf((v.z - mu) * rstd * gg.z + bb.z);
    o.w = f2bf((v.w - mu) * rstd * gg.w + bb.w);
    ((ushort4*)(xn + (size_t)row * DIMSZ))[tid] = o;
  } else if (bid < MTOK + 256) {
    int k = (bid - MTOK) * 4 + wid;
    float a[16];
    #pragma unroll
    for (int r = 0; r < 16; ++r) a[r] = 0.f;
    for (int c = lane; c < DIMSZ; c += 64) {
      float w = w_out[(size_t)k * DIMSZ + c];
      const float* ap = outA + (size_t)c * 16;
      #pragma unroll
      for (int r = 0; r < 16; ++r) a[r] += w * ap[r];
    }
    #pragma unroll
    for (int r = 0; r < 16; ++r) {
      #pragma unroll
      for (int off = 32; off > 0; off >>= 1) a[r] += __shfl_xor(a[r], off, 64);
    }
    if (lane < 16) WA[k * 16 + lane] = a[lane];
  } else if (bid == MTOK + 256) {
    float a[16];
    #pragma unroll
    for (int r = 0; r < 16; ++r) a[r] = 0.f;
    for (int c = tid; c < DIMSZ; c += 256) {
      float bo = b_out[c];
      const float* ap = outA + (size_t)c * 16;
      #pragma unroll
      for (int r = 0; r < 16; ++r) a[r] += bo * ap[r];
    }
    #pragma unroll
    for (int r = 0; r < 16; ++r) {
      #pragma unroll
      for (int off = 32; off > 0; off >>= 1) a[r] += __shfl_xor(a[r], off, 64);
    }
    if (lane == 0) {
      #pragma unroll
      for (int r = 0; r < 16; ++r) sh[wid][r] = a[r];
    }
    __syncthreads();
    if (tid < 16) tt[tid] = sh[0][tid] + sh[1][tid] + sh[2][tid] + sh[3][tid];
    __syncthreads();
    for (int n = tid; n < DIMSZ; n += 256) {
      float l = 0.f;
      #pragma unroll
      for (int r = 0; r < 16; ++r) l += tt[r] * outB[(size_t)r * DIMSZ + n];
      beff[n] = b_out[n] + 0.5f * l;
    }
  } else {
    // WqkvT fold: Wt[n][k] = w_qkv[k][coff+n] + 0.5*sum_r A[k][r]*Bf[r][n]
    __shared__ float Bsf[16][64];
    __shared__ unsigned short Ts[64][72];
    int fid = bid - (MTOK + 257);            // 0..767
    int z = fid >> 8, rem = fid & 255;
    int n0 = (rem & 15) * 64, k0 = (rem >> 4) * 64;
    const float *A, *Bf;
    unsigned short* Wt;
    if (z == 0)      { A = qA; Bf = qB; Wt = WqkvT; }
    else if (z == 1) { A = kA; Bf = kB; Wt = WqkvT + 1048576; }
    else             { A = vA; Bf = vB; Wt = WqkvT + 2097152; }
    int coff = z << 10;
    int tx = tid & 63, ty = tid >> 6;
    for (int r = ty; r < 16; r += 4) Bsf[r][tx] = Bf[(size_t)r * DIMSZ + n0 + tx];
    __syncthreads();
    for (int k = ty; k < 64; k += 4) {
      int kk = k0 + k;
      float w = w_qkv[(size_t)kk * 3072 + coff + n0 + tx];
      const float* Ar = A + (size_t)kk * 16;
      float lora = 0.f;
      #pragma unroll
      for (int r = 0; r < 16; ++r) lora += Ar[r] * Bsf[r][tx];
      Ts[tx][k] = f2bf(w + 0.5f * lora);
    }
    __syncthreads();
    for (int n = ty; n < 64; n += 4)
      Wt[(size_t)(n0 + n) * DIMSZ + k0 + tx] = Ts[n][tx];
  }
}

// ---------------------------------------------------------------------------
// GEMM C = A[M][K] * Bt[N][K]^T, 128x128 tile, BK=64, swapped-operand acc.
// 1-D grid. MODE 0: blocks 0..767 = QKV GEMM (XCD swizzle over 768);
//                  blocks 768..1023 = WoutT fold tail (reuses GEMM LDS).
// MODE 1: blocks 0..255 = out-proj GEMM (+bias, f32 out).
// ---------------------------------------------------------------------------
template<int MODE>
__global__ __launch_bounds__(256) void gemm_kernel(
    const unsigned short* __restrict__ Abf, const unsigned short* __restrict__ Bt,
    int K,
    unsigned short* __restrict__ Qo, unsigned short* __restrict__ Ko,
    unsigned short* __restrict__ Vto,
    const float* __restrict__ bias, float* __restrict__ Cout,
    const float* __restrict__ w_out, const float* __restrict__ WAf,
    const float* __restrict__ outB, unsigned short* __restrict__ WoutT) {
  __shared__ __align__(16) char As[128 * 64 * 2];
  __shared__ __align__(16) char Bs[128 * 64 * 2];
  int lin = blockIdx.x;
  int tid = threadIdx.x;
  if (MODE == 0 && lin >= 768) {
    // WoutT fold: Wt[n][k] = w_out[k][n] + 0.5*sum_r WA[k][r]*outB[r][n]
    float (*Bsf)[64] = (float(*)[64])As;
    unsigned short (*Ts)[72] = (unsigned short(*)[72])(As + 4096);
    int rem = lin - 768;
    int n0 = (rem & 15) * 64, k0 = (rem >> 4) * 64;
    int tx = tid & 63, ty = tid >> 6;
    for (int r = ty; r < 16; r += 4) Bsf[r][tx] = outB[(size_t)r * DIMSZ + n0 + tx];
    __syncthreads();
    for (int k = ty; k < 64; k += 4) {
      int kk = k0 + k;
      float w = w_out[(size_t)kk * DIMSZ + n0 + tx];
      const float* Ar = WAf + (size_t)kk * 16;
      float lora = 0.f;
      #pragma unroll
      for (int r = 0; r < 16; ++r) lora += Ar[r] * Bsf[r][tx];
      Ts[tx][k] = f2bf(w + 0.5f * lora);
    }
    __syncthreads();
    for (int n = ty; n < 64; n += 4)
      WoutT[(size_t)(n0 + n) * DIMSZ + k0 + tx] = Ts[n][tx];
    return;
  }
  const int ngemm = (MODE == 0) ? 768 : 256;
  const int gx    = (MODE == 0) ? 24 : 8;
  int cpx = ngemm >> 3;
  int swz = (lin & 7) * cpx + (lin >> 3);
  int bx = swz % gx;
  int by = swz / gx;
  int n0 = bx * 128;
  int m0 = by * 128;
  int wid = tid >> 6, lane = tid & 63;
  int wr = wid >> 1, wc = wid & 1;
  int hi = lane >> 4;
  f32x4 acc[4][4];   // [n][m]
  #pragma unroll
  for (int i = 0; i < 4; ++i)
    #pragma unroll
    for (int j = 0; j < 4; ++j) acc[i][j] = (f32x4){0.f, 0.f, 0.f, 0.f};

  const char* gA = (const char*)Abf;
  const char* gB = (const char*)Bt;
  int Kb2 = K * 2;
  int nkt = K >> 6;
  for (int kt = 0; kt < nkt; ++kt) {
    #pragma unroll
    for (int j = 0; j < 4; ++j) {
      int it = wid * 4 + j;
      int p = it * 1024 + lane * 16;
      int row = p >> 7, colb = p & 127;
      int L = colb ^ ((row & 7) << 4);
      gload16(gA + (size_t)(m0 + row) * Kb2 + kt * 128 + L, As + it * 1024);
      gload16(gB + (size_t)(n0 + row) * Kb2 + kt * 128 + L, Bs + it * 1024);
    }
    __syncthreads();
    #pragma unroll
    for (int ks = 0; ks < 2; ++ks) {
      int kb = ks * 64 + hi * 16;
      bf16x8 af[4], bfr[4];
      #pragma unroll
      for (int m = 0; m < 4; ++m) {
        int row = wr * 64 + m * 16 + (lane & 15);
        af[m] = *(const bf16x8*)(As + row * 128 + (kb ^ ((row & 7) << 4)));
      }
      #pragma unroll
      for (int n = 0; n < 4; ++n) {
        int row = wc * 64 + n * 16 + (lane & 15);
        bfr[n] = *(const bf16x8*)(Bs + row * 128 + (kb ^ ((row & 7) << 4)));
      }
      __builtin_amdgcn_s_setprio(1);
      #pragma unroll
      for (int n = 0; n < 4; ++n)
        #pragma unroll
        for (int m = 0; m < 4; ++m)
          acc[n][m] = __builtin_amdgcn_mfma_f32_16x16x32_bf16(bfr[n], af[m], acc[n][m], 0, 0, 0);
      __builtin_amdgcn_s_setprio(0);
    }
    __syncthreads();
  }

  if (MODE == 0) {
    int sec  = n0 >> 10;                  // 0=q 1=k 2=v (tile never straddles)
    int nloc = (n0 & 1023) + wc * 64;
    int h = nloc >> 6;                    // each wave covers exactly one head
    int mbase = m0 + wr * 64;
    #pragma unroll
    for (int m = 0; m < 4; ++m) {
      int gm = mbase + m * 16 + (lane & 15);
      int bb = gm >> 11, t = gm & 2047;
      #pragma unroll
      for (int n = 0; n < 4; ++n) {
        int dloc = n * 16 + hi * 4;
        if (sec == 2) {
          #pragma unroll
          for (int r = 0; r < 4; ++r)
            Vto[((size_t)((bb * 16 + h) * 64 + dloc + r)) * TSEQ + t] = f2bf(acc[n][m][r]);
        } else {
          bf16x4 o;
          #pragma unroll
          for (int r = 0; r < 4; ++r) o[r] = (short)f2bf(acc[n][m][r]);
          size_t idx = ((size_t)(bb * 16 + h) * TSEQ + t) * 64 + dloc;
          *(bf16x4*)((sec == 0 ? Qo : Ko) + idx) = o;
        }
      }
    }
  } else {
    int mbase = m0 + wr * 64;
    int nbase = n0 + wc * 64;
    #pragma unroll
    for (int m = 0; m < 4; ++m) {
      int t = mbase + m * 16 + (lane & 15);
      #pragma unroll
      for (int n = 0; n < 4; ++n) {
        int c = nbase + n * 16 + hi * 4;
        float4 bs = *(const float4*)(bias + c);
        float4 o;
        o.x = acc[n][m][0] + bs.x;
        o.y = acc[n][m][1] + bs.y;
        o.z = acc[n][m][2] + bs.z;
        o.w = acc[n][m][3] + bs.w;
        *(float4*)(Cout + (size_t)t * DIMSZ + c) = o;
      }
    }
  }
}

// ---------------------------------------------------------------------------
// Flash attention. QBLK=64 (4 waves x 16 q-rows), KVBLK=64, deferred-PV.
// K staged in LDS (double-buffered); V read DIRECT from global (L2-resident:
// each bh's V is shared by 32 q-blocks) -> no V staging, no V LDS reads,
// LDS 40->24 KB, shorter vmcnt drains at barriers.
// Grid: x=bh(32), y=32: y<16 -> qt=31-y (heavy first), else qt=y-16.
// ---------------------------------------------------------------------------
__global__ __launch_bounds__(256, 4) void attn_kernel(
    const unsigned short* __restrict__ Qg, const unsigned short* __restrict__ Kg,
    const unsigned short* __restrict__ Vt, unsigned short* __restrict__ Orow) {
  __shared__ __align__(16) char KsB[2][64 * 128];   // [key][d]  16 KB
  __shared__ __align__(16) char Ps[4][16 * 128];    // per-wave P [q][key] 8 KB
  int bh = blockIdx.x;
  int y  = blockIdx.y;
  int qt = (y < 16) ? (31 - y) : (y - 16);          // heavy tiles dispatch first
  int b = bh >> 4, h = bh & 15;
  int tid = threadIdx.x, wid = tid >> 6, lane = tid & 63;
  int hi = lane >> 4, lo = lane & 15;
  const char* Qb = (const char*)(Qg + (size_t)bh * TSEQ * 64);
  const char* Kb = (const char*)(Kg + (size_t)bh * TSEQ * 64);
  const char* Vb = (const char*)(Vt + (size_t)bh * 64 * TSEQ);
  int q0 = qt * 64;

  // K staging geometry: thread -> 2 K-rows (16B each, swizzled src)
  int srow = tid >> 3;                                   // 0..31
  int scol = ((tid & 7) << 4) ^ ((srow & 7) << 4);

  // Q B-frags with 0.125*log2e folded (exp2-domain softmax)
  const float qscale = 0.18033688f;
  bf16x8 qf[2];
  {
    int row = q0 + wid * 16 + lo;
    #pragma unroll
    for (int ks = 0; ks < 2; ++ks) {
      bf16x8 raw = *(const bf16x8*)(Qb + (size_t)row * 128 + ks * 64 + hi * 16);
      bf16x8 sc;
      #pragma unroll
      for (int i = 0; i < 8; ++i)
        sc[i] = (short)f2bf(bf2f((unsigned short)raw[i]) * qscale);
      qf[ks] = sc;
    }
  }

  f32x4 Oacc[4];                 // O^T: d = df*16 + hi*4 + r, q = lo
  #pragma unroll
  for (int df = 0; df < 4; ++df) Oacc[df] = (f32x4){0.f, 0.f, 0.f, 0.f};
  float mrun = -INFINITY, lrun = 0.f;   // lrun = per-lane partial (16 keys)

  char* Pw = Ps[wid];
  char* pbase = Pw + lo * 128;
  int pswz = (lo & 7) << 4;

  // V direct-read base for this lane: row d = df*16+lo, key offset per (ks2,hi)
  // byte addr = Vb + d*(TSEQ*2) + k0*2 + ks2*64 + hi*16
  const char* Vlane = Vb + (size_t)lo * (TSEQ * 2) + hi * 16;

  int nkt = ((qt >> 2) + 1) << 2;   // (frame+1) * 256/64

  // prologue: stage K(0) into buffer 0
  {
    const char* ksrc = Kb + (size_t)srow * 128 + scol;
    gload16(ksrc,            KsB[0] + tid * 16);
    gload16(ksrc + 32 * 128, KsB[0] + tid * 16 + 4096);
  }

  for (int kt = 0; kt < nkt; ++kt) {
    __syncthreads();   // K(kt) staged; prior-iter K reads complete
    if (kt + 1 < nkt) {   // stage K(kt+1)
      int k0n = (kt + 1) << 6;
      char* kd = KsB[(kt + 1) & 1];
      const char* ksrc = Kb + (size_t)(k0n + srow) * 128 + scol;
      gload16(ksrc,            kd + tid * 16);
      gload16(ksrc + 32 * 128, kd + tid * 16 + 4096);
    }
    const char* Kbuf = KsB[kt & 1];

    // S^T = K Q^T : s[nf], key = nf*16 + hi*4 + r, q = lo
    f32x4 s[4];
    #pragma unroll
    for (int nf = 0; nf < 4; ++nf) s[nf] = (f32x4){0.f, 0.f, 0.f, 0.f};
    #pragma unroll
    for (int ks = 0; ks < 2; ++ks) {
      int kb = ks * 64 + hi * 16;
      bf16x8 kf[4];
      #pragma unroll
      for (int nf = 0; nf < 4; ++nf) {
        int row = nf * 16 + lo;
        kf[nf] = *(const bf16x8*)(Kbuf + row * 128 + (kb ^ ((row & 7) << 4)));
      }
      __builtin_amdgcn_s_setprio(1);
      #pragma unroll
      for (int nf = 0; nf < 4; ++nf)
        s[nf] = __builtin_amdgcn_mfma_f32_16x16x32_bf16(kf[nf], qf[ks], s[nf], 0, 0, 0);
      __builtin_amdgcn_s_setprio(0);
    }

    // PV(kt-1): P from per-wave LDS, V DIRECT from global (L2-hot).
    if (kt) {
      const char* Vk = Vlane + ((kt - 1) << 7);   // + k0*2 bytes
      #pragma unroll
      for (int ks2 = 0; ks2 < 2; ++ks2) {
        int kb = ks2 * 64 + hi * 16;
        bf16x8 pf = *(const bf16x8*)(Pw + lo * 128 + (kb ^ pswz));
        bf16x8 vf[4];
        #pragma unroll
        for (int df = 0; df < 4; ++df)
          vf[df] = *(const bf16x8*)(Vk + (size_t)df * (16 * TSEQ * 2) + ks2 * 64);
        __builtin_amdgcn_s_setprio(1);
        #pragma unroll
        for (int df = 0; df < 4; ++df)
          Oacc[df] = __builtin_amdgcn_mfma_f32_16x16x32_bf16(vf[df], pf, Oacc[df], 0, 0, 0);
        __builtin_amdgcn_s_setprio(0);
      }
    }

    // max over 16 scores (tree), then across hi-groups
    float a0 = fmaxf(fmaxf(s[0][0], s[0][1]), fmaxf(s[0][2], s[0][3]));
    float a1 = fmaxf(fmaxf(s[1][0], s[1][1]), fmaxf(s[1][2], s[1][3]));
    float a2 = fmaxf(fmaxf(s[2][0], s[2][1]), fmaxf(s[2][2], s[2][3]));
    float a3 = fmaxf(fmaxf(s[3][0], s[3][1]), fmaxf(s[3][2], s[3][3]));
    float mx = fmaxf(fmaxf(a0, a1), fmaxf(a2, a3));
    mx = fmaxf(mx, __shfl_xor(mx, 16, 64));
    mx = fmaxf(mx, __shfl_xor(mx, 32, 64));

    // defer-max (THR=8 in log2 units): skip O-rescale when max barely grows
    if (!__all(mx <= mrun + 8.0f)) {
      float mn = fmaxf(mrun, mx);
      float al = exp2f(mrun - mn);
      mrun = mn;
      lrun *= al;
      #pragma unroll
      for (int df = 0; df < 4; ++df)
        #pragma unroll
        for (int r = 0; r < 4; ++r) Oacc[df][r] *= al;
    }

    // exp2 + per-lane partial row-sum (no shuffles here)
    float rs0 = 0.f, rs1 = 0.f, rs2 = 0.f, rs3 = 0.f;
    #pragma unroll
    for (int nf = 0; nf < 4; ++nf) {
      float p0 = exp2f(s[nf][0] - mrun);
      float p1 = exp2f(s[nf][1] - mrun);
      float p2 = exp2f(s[nf][2] - mrun);
      float p3 = exp2f(s[nf][3] - mrun);
      s[nf][0] = p0; s[nf][1] = p1; s[nf][2] = p2; s[nf][3] = p3;
      rs0 += p0; rs1 += p1; rs2 += p2; rs3 += p3;
    }
    lrun += (rs0 + rs1) + (rs2 + rs3);

    // pack P(kt) -> per-wave LDS (packed cvt, 8B stores)
    #pragma unroll
    for (int nf = 0; nf < 4; ++nf) {
      unsigned int w0 = cvtpk_bf16(s[nf][0], s[nf][1]);
      unsigned int w1 = cvtpk_bf16(s[nf][2], s[nf][3]);
      uint2 pr; pr.x = w0; pr.y = w1;
      *(uint2*)(pbase + ((nf * 32 + hi * 8) ^ pswz)) = pr;
    }
  }

  // final PV(nkt-1): P is per-wave (in-wave lgkm ordering); V direct.
  __syncthreads();
  {
    const char* Vk = Vlane + ((nkt - 1) << 7);
    #pragma unroll
    for (int ks2 = 0; ks2 < 2; ++ks2) {
      int kb = ks2 * 64 + hi * 16;
      bf16x8 pf = *(const bf16x8*)(Pw + lo * 128 + (kb ^ pswz));
      bf16x8 vf[4];
      #pragma unroll
      for (int df = 0; df < 4; ++df)
        vf[df] = *(const bf16x8*)(Vk + (size_t)df * (16 * TSEQ * 2) + ks2 * 64);
      __builtin_amdgcn_s_setprio(1);
      #pragma unroll
      for (int df = 0; df < 4; ++df)
        Oacc[df] = __builtin_amdgcn_mfma_f32_16x16x32_bf16(vf[df], pf, Oacc[df], 0, 0, 0);
      __builtin_amdgcn_s_setprio(0);
    }
  }

  // reduce lrun partials across hi-groups, then finalize with 8B stores
  lrun += __shfl_xor(lrun, 16, 64);
  lrun += __shfl_xor(lrun, 32, 64);
  float inv = 1.0f / lrun;
  int t = q0 + wid * 16 + lo;
  size_t rowbase = ((size_t)(b * TSEQ + t)) * DIMSZ + h * 64;
  #pragma unroll
  for (int df = 0; df < 4; ++df) {
    bf16x4 o;
    #pragma unroll
    for (int r = 0; r < 4; ++r) o[r] = (short)f2bf(Oacc[df][r] * inv);
    *(bf16x4*)(Orow + rowbase + df * 16 + hi * 4) = o;
  }
}

// ---------------------------------------------------------------------------
extern "C" void kernel_launch(void* const* d_in, const int* in_sizes, int n_in,
                              void* d_out, int out_size, void* d_ws, size_t ws_size,
                              hipStream_t stream) {
  (void)in_sizes; (void)n_in; (void)out_size; (void)ws_size;
  const float* x     = (const float*)d_in[0];
  const float* ln_g  = (const float*)d_in[2];
  const float* ln_b  = (const float*)d_in[3];
  const float* w_qkv = (const float*)d_in[4];
  const float* qA    = (const float*)d_in[5];
  const float* qB    = (const float*)d_in[6];
  const float* kA    = (const float*)d_in[7];
  const float* kB    = (const float*)d_in[8];
  const float* vA    = (const float*)d_in[9];
  const float* vB    = (const float*)d_in[10];
  const float* w_out = (const float*)d_in[11];
  const float* b_out = (const float*)d_in[12];
  const float* outA  = (const float*)d_in[13];
  const float* outB  = (const float*)d_in[14];

  char* ws = (char*)d_ws;
  unsigned short* xn    = (unsigned short*)(ws);             // 8388608 B
  unsigned short* WqkvT = (unsigned short*)(ws + 8388608);   // 6291456 B
  unsigned short* WoutT = (unsigned short*)(ws + 14680064);  // 2097152 B
  float*          WA    = (float*)(ws + 16777216);           // 65536 B
  float*          beff  = (float*)(ws + 16842752);           // 4096 B
  unsigned short* Qb    = (unsigned short*)(ws + 16846848);  // 8388608 B
  unsigned short* Kb    = (unsigned short*)(ws + 25235456);  // 8388608 B
  unsigned short* Vtb   = (unsigned short*)(ws + 33624064);  // 8388608 B
  unsigned short* Orow  = xn;    // alias: xn dead after GEMM0
  float* outp = (float*)d_out;

  prep_kernel<<<MTOK + 257 + 768, 256, 0, stream>>>(x, ln_g, ln_b, w_out, outA,
      b_out, outB, w_qkv, qA, qB, kA, kB, vA, vB, xn, WA, beff, WqkvT);
  gemm_kernel<0><<<1024, 256, 0, stream>>>(xn, WqkvT, DIMSZ, Qb, Kb, Vtb,
      nullptr, nullptr, w_out, WA, outB, WoutT);
  attn_kernel<<<dim3(32, 32), 256, 0, stream>>>(Qb, Kb, Vtb, Orow);
  gemm_kernel<1><<<256, 256, 0, stream>>>(Orow, WoutT, DIMSZ, nullptr, nullptr,
      nullptr, beff, outp, nullptr, nullptr, nullptr, nullptr);
}

// Round 13
// 159.697 us; speedup vs baseline: 1.0567x; 1.0567x over previous
//
#include <hip/hip_runtime.h>

// ---------------------------------------------------------------------------
// AttentionWithLoRA, 4-kernel chain:
//   prep  (LN + WA=w_out@outA + beff + WqkvT fold z0-2)
//   gemm0 (QKV GEMM + WoutT fold tail)
//   attn  (flash attention; K staged in LDS, V register-prefetched from L2)
//   gemm1 (out-proj + bias)
// ---------------------------------------------------------------------------

#define DIMSZ 1024
#define TSEQ  2048
#define MTOK  4096   // B*T rows

typedef __attribute__((ext_vector_type(8))) short bf16x8;
typedef __attribute__((ext_vector_type(4))) short bf16x4;
typedef __attribute__((ext_vector_type(4))) float f32x4;

__device__ __forceinline__ unsigned short f2bf(float f) {
  unsigned int u = __float_as_uint(f);
  u += 0x7fffu + ((u >> 16) & 1u);   // round-nearest-even
  return (unsigned short)(u >> 16);
}
__device__ __forceinline__ float bf2f(unsigned short s) {
  return __uint_as_float(((unsigned int)s) << 16);
}
__device__ __forceinline__ unsigned int cvtpk_bf16(float a, float b) {
  unsigned int d;
  asm("v_cvt_pk_bf16_f32 %0, %1, %2" : "=v"(d) : "v"(a), "v"(b));
  return d;
}
__device__ __forceinline__ void gload16(const void* g, void* l) {
  __builtin_amdgcn_global_load_lds((const __attribute__((address_space(1))) void*)g,
                                   (__attribute__((address_space(3))) void*)l, 16, 0, 0);
}

// ---------------------------------------------------------------------------
// prep: blocks 0..4095 LayerNorm; 4096..4351 WA=w_out@outA (4 rows/blk);
// 4352: beff; 4353..5120: WqkvT fold (z = (bid-4353)>>8, 16x16 64-blocks).
// ---------------------------------------------------------------------------
__global__ __launch_bounds__(256) void prep_kernel(const float* __restrict__ x,
    const float* __restrict__ g, const float* __restrict__ bln,
    const float* __restrict__ w_out, const float* __restrict__ outA,
    const float* __restrict__ b_out, const float* __restrict__ outB,
    const float* __restrict__ w_qkv,
    const float* __restrict__ qA, const float* __restrict__ qB,
    const float* __restrict__ kA, const float* __restrict__ kB,
    const float* __restrict__ vA, const float* __restrict__ vB,
    unsigned short* __restrict__ xn, float* __restrict__ WA,
    float* __restrict__ beff, unsigned short* __restrict__ WqkvT) {
  __shared__ float red[8];
  __shared__ float sh[4][16];
  __shared__ float tt[16];
  int bid = blockIdx.x;
  int tid = threadIdx.x, wid = tid >> 6, lane = tid & 63;
  if (bid < MTOK) {
    int row = bid;
    const float4* xr = (const float4*)(x + (size_t)row * DIMSZ);
    float4 v = xr[tid];
    float s  = v.x + v.y + v.z + v.w;
    float s2 = v.x*v.x + v.y*v.y + v.z*v.z + v.w*v.w;
    #pragma unroll
    for (int off = 32; off > 0; off >>= 1) {
      s  += __shfl_xor(s, off, 64);
      s2 += __shfl_xor(s2, off, 64);
    }
    if (lane == 0) { red[wid] = s; red[wid + 4] = s2; }
    __syncthreads();
    s  = red[0] + red[1] + red[2] + red[3];
    s2 = red[4] + red[5] + red[6] + red[7];
    float mu  = s * (1.0f / DIMSZ);
    float var = s2 * (1.0f / DIMSZ) - mu * mu;
    float rstd = rsqrtf(var + 1e-5f);
    float4 gg = ((const float4*)g)[tid];
    float4 bb = ((const float4*)bln)[tid];
    ushort4 o;
    o.x = f2bf((v.x - mu) * rstd * gg.x + bb.x);
    o.y = f2bf((v.y - mu) * rstd * gg.y + bb.y);
    o.z = f2bf((v.z - mu) * rstd * gg.z + bb.z);
    o.w = f2bf((v.w - mu) * rstd * gg.w + bb.w);
    ((ushort4*)(xn + (size_t)row * DIMSZ))[tid] = o;
  } else if (bid < MTOK + 256) {
    int k = (bid - MTOK) * 4 + wid;
    float a[16];
    #pragma unroll
    for (int r = 0; r < 16; ++r) a[r] = 0.f;
    for (int c = lane; c < DIMSZ; c += 64) {
      float w = w_out[(size_t)k * DIMSZ + c];
      const float* ap = outA + (size_t)c * 16;
      #pragma unroll
      for (int r = 0; r < 16; ++r) a[r] += w * ap[r];
    }
    #pragma unroll
    for (int r = 0; r < 16; ++r) {
      #pragma unroll
      for (int off = 32; off > 0; off >>= 1) a[r] += __shfl_xor(a[r], off, 64);
    }
    if (lane < 16) WA[k * 16 + lane] = a[lane];
  } else if (bid == MTOK + 256) {
    float a[16];
    #pragma unroll
    for (int r = 0; r < 16; ++r) a[r] = 0.f;
    for (int c = tid; c < DIMSZ; c += 256) {
      float bo = b_out[c];
      const float* ap = outA + (size_t)c * 16;
      #pragma unroll
      for (int r = 0; r < 16; ++r) a[r] += bo * ap[r];
    }
    #pragma unroll
    for (int r = 0; r < 16; ++r) {
      #pragma unroll
      for (int off = 32; off > 0; off >>= 1) a[r] += __shfl_xor(a[r], off, 64);
    }
    if (lane == 0) {
      #pragma unroll
      for (int r = 0; r < 16; ++r) sh[wid][r] = a[r];
    }
    __syncthreads();
    if (tid < 16) tt[tid] = sh[0][tid] + sh[1][tid] + sh[2][tid] + sh[3][tid];
    __syncthreads();
    for (int n = tid; n < DIMSZ; n += 256) {
      float l = 0.f;
      #pragma unroll
      for (int r = 0; r < 16; ++r) l += tt[r] * outB[(size_t)r * DIMSZ + n];
      beff[n] = b_out[n] + 0.5f * l;
    }
  } else {
    // WqkvT fold: Wt[n][k] = w_qkv[k][coff+n] + 0.5*sum_r A[k][r]*Bf[r][n]
    __shared__ float Bsf[16][64];
    __shared__ unsigned short Ts[64][72];
    int fid = bid - (MTOK + 257);            // 0..767
    int z = fid >> 8, rem = fid & 255;
    int n0 = (rem & 15) * 64, k0 = (rem >> 4) * 64;
    const float *A, *Bf;
    unsigned short* Wt;
    if (z == 0)      { A = qA; Bf = qB; Wt = WqkvT; }
    else if (z == 1) { A = kA; Bf = kB; Wt = WqkvT + 1048576; }
    else             { A = vA; Bf = vB; Wt = WqkvT + 2097152; }
    int coff = z << 10;
    int tx = tid & 63, ty = tid >> 6;
    for (int r = ty; r < 16; r += 4) Bsf[r][tx] = Bf[(size_t)r * DIMSZ + n0 + tx];
    __syncthreads();
    for (int k = ty; k < 64; k += 4) {
      int kk = k0 + k;
      float w = w_qkv[(size_t)kk * 3072 + coff + n0 + tx];
      const float* Ar = A + (size_t)kk * 16;
      float lora = 0.f;
      #pragma unroll
      for (int r = 0; r < 16; ++r) lora += Ar[r] * Bsf[r][tx];
      Ts[tx][k] = f2bf(w + 0.5f * lora);
    }
    __syncthreads();
    for (int n = ty; n < 64; n += 4)
      Wt[(size_t)(n0 + n) * DIMSZ + k0 + tx] = Ts[n][tx];
  }
}

// ---------------------------------------------------------------------------
// GEMM C = A[M][K] * Bt[N][K]^T, 128x128 tile, BK=64, swapped-operand acc.
// 1-D grid. MODE 0: blocks 0..767 = QKV GEMM (XCD swizzle over 768);
//                  blocks 768..1023 = WoutT fold tail (reuses GEMM LDS).
// MODE 1: blocks 0..255 = out-proj GEMM (+bias, f32 out).
// ---------------------------------------------------------------------------
template<int MODE>
__global__ __launch_bounds__(256) void gemm_kernel(
    const unsigned short* __restrict__ Abf, const unsigned short* __restrict__ Bt,
    int K,
    unsigned short* __restrict__ Qo, unsigned short* __restrict__ Ko,
    unsigned short* __restrict__ Vto,
    const float* __restrict__ bias, float* __restrict__ Cout,
    const float* __restrict__ w_out, const float* __restrict__ WAf,
    const float* __restrict__ outB, unsigned short* __restrict__ WoutT) {
  __shared__ __align__(16) char As[128 * 64 * 2];
  __shared__ __align__(16) char Bs[128 * 64 * 2];
  int lin = blockIdx.x;
  int tid = threadIdx.x;
  if (MODE == 0 && lin >= 768) {
    // WoutT fold: Wt[n][k] = w_out[k][n] + 0.5*sum_r WA[k][r]*outB[r][n]
    float (*Bsf)[64] = (float(*)[64])As;
    unsigned short (*Ts)[72] = (unsigned short(*)[72])(As + 4096);
    int rem = lin - 768;
    int n0 = (rem & 15) * 64, k0 = (rem >> 4) * 64;
    int tx = tid & 63, ty = tid >> 6;
    for (int r = ty; r < 16; r += 4) Bsf[r][tx] = outB[(size_t)r * DIMSZ + n0 + tx];
    __syncthreads();
    for (int k = ty; k < 64; k += 4) {
      int kk = k0 + k;
      float w = w_out[(size_t)kk * DIMSZ + n0 + tx];
      const float* Ar = WAf + (size_t)kk * 16;
      float lora = 0.f;
      #pragma unroll
      for (int r = 0; r < 16; ++r) lora += Ar[r] * Bsf[r][tx];
      Ts[tx][k] = f2bf(w + 0.5f * lora);
    }
    __syncthreads();
    for (int n = ty; n < 64; n += 4)
      WoutT[(size_t)(n0 + n) * DIMSZ + k0 + tx] = Ts[n][tx];
    return;
  }
  const int ngemm = (MODE == 0) ? 768 : 256;
  const int gx    = (MODE == 0) ? 24 : 8;
  int cpx = ngemm >> 3;
  int swz = (lin & 7) * cpx + (lin >> 3);
  int bx = swz % gx;
  int by = swz / gx;
  int n0 = bx * 128;
  int m0 = by * 128;
  int wid = tid >> 6, lane = tid & 63;
  int wr = wid >> 1, wc = wid & 1;
  int hi = lane >> 4;
  f32x4 acc[4][4];   // [n][m]
  #pragma unroll
  for (int i = 0; i < 4; ++i)
    #pragma unroll
    for (int j = 0; j < 4; ++j) acc[i][j] = (f32x4){0.f, 0.f, 0.f, 0.f};

  const char* gA = (const char*)Abf;
  const char* gB = (const char*)Bt;
  int Kb2 = K * 2;
  int nkt = K >> 6;
  for (int kt = 0; kt < nkt; ++kt) {
    #pragma unroll
    for (int j = 0; j < 4; ++j) {
      int it = wid * 4 + j;
      int p = it * 1024 + lane * 16;
      int row = p >> 7, colb = p & 127;
      int L = colb ^ ((row & 7) << 4);
      gload16(gA + (size_t)(m0 + row) * Kb2 + kt * 128 + L, As + it * 1024);
      gload16(gB + (size_t)(n0 + row) * Kb2 + kt * 128 + L, Bs + it * 1024);
    }
    __syncthreads();
    #pragma unroll
    for (int ks = 0; ks < 2; ++ks) {
      int kb = ks * 64 + hi * 16;
      bf16x8 af[4], bfr[4];
      #pragma unroll
      for (int m = 0; m < 4; ++m) {
        int row = wr * 64 + m * 16 + (lane & 15);
        af[m] = *(const bf16x8*)(As + row * 128 + (kb ^ ((row & 7) << 4)));
      }
      #pragma unroll
      for (int n = 0; n < 4; ++n) {
        int row = wc * 64 + n * 16 + (lane & 15);
        bfr[n] = *(const bf16x8*)(Bs + row * 128 + (kb ^ ((row & 7) << 4)));
      }
      __builtin_amdgcn_s_setprio(1);
      #pragma unroll
      for (int n = 0; n < 4; ++n)
        #pragma unroll
        for (int m = 0; m < 4; ++m)
          acc[n][m] = __builtin_amdgcn_mfma_f32_16x16x32_bf16(bfr[n], af[m], acc[n][m], 0, 0, 0);
      __builtin_amdgcn_s_setprio(0);
    }
    __syncthreads();
  }

  if (MODE == 0) {
    int sec  = n0 >> 10;                  // 0=q 1=k 2=v (tile never straddles)
    int nloc = (n0 & 1023) + wc * 64;
    int h = nloc >> 6;                    // each wave covers exactly one head
    int mbase = m0 + wr * 64;
    #pragma unroll
    for (int m = 0; m < 4; ++m) {
      int gm = mbase + m * 16 + (lane & 15);
      int bb = gm >> 11, t = gm & 2047;
      #pragma unroll
      for (int n = 0; n < 4; ++n) {
        int dloc = n * 16 + hi * 4;
        if (sec == 2) {
          #pragma unroll
          for (int r = 0; r < 4; ++r)
            Vto[((size_t)((bb * 16 + h) * 64 + dloc + r)) * TSEQ + t] = f2bf(acc[n][m][r]);
        } else {
          bf16x4 o;
          #pragma unroll
          for (int r = 0; r < 4; ++r) o[r] = (short)f2bf(acc[n][m][r]);
          size_t idx = ((size_t)(bb * 16 + h) * TSEQ + t) * 64 + dloc;
          *(bf16x4*)((sec == 0 ? Qo : Ko) + idx) = o;
        }
      }
    }
  } else {
    int mbase = m0 + wr * 64;
    int nbase = n0 + wc * 64;
    #pragma unroll
    for (int m = 0; m < 4; ++m) {
      int t = mbase + m * 16 + (lane & 15);
      #pragma unroll
      for (int n = 0; n < 4; ++n) {
        int c = nbase + n * 16 + hi * 4;
        float4 bs = *(const float4*)(bias + c);
        float4 o;
        o.x = acc[n][m][0] + bs.x;
        o.y = acc[n][m][1] + bs.y;
        o.z = acc[n][m][2] + bs.z;
        o.w = acc[n][m][3] + bs.w;
        *(float4*)(Cout + (size_t)t * DIMSZ + c) = o;
      }
    }
  }
}

// ---------------------------------------------------------------------------
// Flash attention. QBLK=64 (4 waves x 16 q-rows), KVBLK=64, deferred-PV.
// K staged in LDS (double-buffered). V REGISTER-PREFETCHED: at iter kt the
// 8 per-lane V(kt) fragments are loaded into regs right after PV(kt-1)
// frees them; the next barrier's vmcnt(0) drain guarantees completion
// before PV(kt) uses them at iter kt+1. No V LDS, no final barrier.
// Grid: x=bh(32), y=32: y<16 -> qt=31-y (heavy first), else qt=y-16.
// ---------------------------------------------------------------------------
__global__ __launch_bounds__(256, 4) void attn_kernel(
    const unsigned short* __restrict__ Qg, const unsigned short* __restrict__ Kg,
    const unsigned short* __restrict__ Vt, unsigned short* __restrict__ Orow) {
  __shared__ __align__(16) char KsB[2][64 * 128];   // [key][d]  16 KB
  __shared__ __align__(16) char Ps[4][16 * 128];    // per-wave P [q][key] 8 KB
  int bh = blockIdx.x;
  int y  = blockIdx.y;
  int qt = (y < 16) ? (31 - y) : (y - 16);          // heavy tiles dispatch first
  int b = bh >> 4, h = bh & 15;
  int tid = threadIdx.x, wid = tid >> 6, lane = tid & 63;
  int hi = lane >> 4, lo = lane & 15;
  const char* Qb = (const char*)(Qg + (size_t)bh * TSEQ * 64);
  const char* Kb = (const char*)(Kg + (size_t)bh * TSEQ * 64);
  const char* Vb = (const char*)(Vt + (size_t)bh * 64 * TSEQ);
  int q0 = qt * 64;

  // K staging geometry: thread -> 2 K-rows (16B each, swizzled src)
  int srow = tid >> 3;                                   // 0..31
  int scol = ((tid & 7) << 4) ^ ((srow & 7) << 4);

  // Q B-frags with 0.125*log2e folded (exp2-domain softmax)
  const float qscale = 0.18033688f;
  bf16x8 qf[2];
  {
    int row = q0 + wid * 16 + lo;
    #pragma unroll
    for (int ks = 0; ks < 2; ++ks) {
      bf16x8 raw = *(const bf16x8*)(Qb + (size_t)row * 128 + ks * 64 + hi * 16);
      bf16x8 sc;
      #pragma unroll
      for (int i = 0; i < 8; ++i)
        sc[i] = (short)f2bf(bf2f((unsigned short)raw[i]) * qscale);
      qf[ks] = sc;
    }
  }

  f32x4 Oacc[4];                 // O^T: d = df*16 + hi*4 + r, q = lo
  #pragma unroll
  for (int df = 0; df < 4; ++df) Oacc[df] = (f32x4){0.f, 0.f, 0.f, 0.f};
  float mrun = -INFINITY, lrun = 0.f;   // lrun = per-lane partial (16 keys)

  char* Pw = Ps[wid];
  char* pbase = Pw + lo * 128;
  int pswz = (lo & 7) << 4;

  // V direct-read base for this lane: V[d = df*16+lo][key], frag (ks2,hi):
  // byte addr = Vb + d*(TSEQ*2) + kt*128 + ks2*64 + hi*16
  const char* Vlane = Vb + (size_t)lo * (TSEQ * 2) + hi * 16;
  bf16x8 vreg[8];                // V(kt) frags: [ks2*4 + df]

  int nkt = ((qt >> 2) + 1) << 2;   // (frame+1) * 256/64

  // prologue: stage K(0) into buffer 0
  {
    const char* ksrc = Kb + (size_t)srow * 128 + scol;
    gload16(ksrc,            KsB[0] + tid * 16);
    gload16(ksrc + 32 * 128, KsB[0] + tid * 16 + 4096);
  }

  for (int kt = 0; kt < nkt; ++kt) {
    __syncthreads();   // K(kt) staged; V(kt-1) reg loads drained (vmcnt 0)
    if (kt + 1 < nkt) {   // stage K(kt+1)
      int k0n = (kt + 1) << 6;
      char* kd = KsB[(kt + 1) & 1];
      const char* ksrc = Kb + (size_t)(k0n + srow) * 128 + scol;
      gload16(ksrc,            kd + tid * 16);
      gload16(ksrc + 32 * 128, kd + tid * 16 + 4096);
    }
    const char* Kbuf = KsB[kt & 1];

    // S^T = K Q^T : s[nf], key = nf*16 + hi*4 + r, q = lo
    f32x4 s[4];
    #pragma unroll
    for (int nf = 0; nf < 4; ++nf) s[nf] = (f32x4){0.f, 0.f, 0.f, 0.f};
    #pragma unroll
    for (int ks = 0; ks < 2; ++ks) {
      int kb = ks * 64 + hi * 16;
      bf16x8 kf[4];
      #pragma unroll
      for (int nf = 0; nf < 4; ++nf) {
        int row = nf * 16 + lo;
        kf[nf] = *(const bf16x8*)(Kbuf + row * 128 + (kb ^ ((row & 7) << 4)));
      }
      __builtin_amdgcn_s_setprio(1);
      #pragma unroll
      for (int nf = 0; nf < 4; ++nf)
        s[nf] = __builtin_amdgcn_mfma_f32_16x16x32_bf16(kf[nf], qf[ks], s[nf], 0, 0, 0);
      __builtin_amdgcn_s_setprio(0);
    }

    // PV(kt-1): P from per-wave LDS, V(kt-1) already in regs (prefetched)
    if (kt) {
      #pragma unroll
      for (int ks2 = 0; ks2 < 2; ++ks2) {
        int kb = ks2 * 64 + hi * 16;
        bf16x8 pf = *(const bf16x8*)(Pw + lo * 128 + (kb ^ pswz));
        __builtin_amdgcn_s_setprio(1);
        #pragma unroll
        for (int df = 0; df < 4; ++df)
          Oacc[df] = __builtin_amdgcn_mfma_f32_16x16x32_bf16(vreg[ks2 * 4 + df], pf, Oacc[df], 0, 0, 0);
        __builtin_amdgcn_s_setprio(0);
      }
    }

    // issue V(kt) reg loads (consumed by PV(kt) at iter kt+1; the next
    // barrier's vmcnt(0) drain guarantees completion before use)
    {
      const char* Vk = Vlane + (kt << 7);
      #pragma unroll
      for (int df = 0; df < 4; ++df) {
        vreg[df]     = *(const bf16x8*)(Vk + (size_t)df * (16 * TSEQ * 2));
        vreg[df + 4] = *(const bf16x8*)(Vk + (size_t)df * (16 * TSEQ * 2) + 64);
      }
    }

    // max over 16 scores (tree), then across hi-groups
    float a0 = fmaxf(fmaxf(s[0][0], s[0][1]), fmaxf(s[0][2], s[0][3]));
    float a1 = fmaxf(fmaxf(s[1][0], s[1][1]), fmaxf(s[1][2], s[1][3]));
    float a2 = fmaxf(fmaxf(s[2][0], s[2][1]), fmaxf(s[2][2], s[2][3]));
    float a3 = fmaxf(fmaxf(s[3][0], s[3][1]), fmaxf(s[3][2], s[3][3]));
    float mx = fmaxf(fmaxf(a0, a1), fmaxf(a2, a3));
    mx = fmaxf(mx, __shfl_xor(mx, 16, 64));
    mx = fmaxf(mx, __shfl_xor(mx, 32, 64));

    // defer-max (THR=8 in log2 units): skip O-rescale when max barely grows
    if (!__all(mx <= mrun + 8.0f)) {
      float mn = fmaxf(mrun, mx);
      float al = exp2f(mrun - mn);
      mrun = mn;
      lrun *= al;
      #pragma unroll
      for (int df = 0; df < 4; ++df)
        #pragma unroll
        for (int r = 0; r < 4; ++r) Oacc[df][r] *= al;
    }

    // exp2 + per-lane partial row-sum (no shuffles here)
    float rs0 = 0.f, rs1 = 0.f, rs2 = 0.f, rs3 = 0.f;
    #pragma unroll
    for (int nf = 0; nf < 4; ++nf) {
      float p0 = exp2f(s[nf][0] - mrun);
      float p1 = exp2f(s[nf][1] - mrun);
      float p2 = exp2f(s[nf][2] - mrun);
      float p3 = exp2f(s[nf][3] - mrun);
      s[nf][0] = p0; s[nf][1] = p1; s[nf][2] = p2; s[nf][3] = p3;
      rs0 += p0; rs1 += p1; rs2 += p2; rs3 += p3;
    }
    lrun += (rs0 + rs1) + (rs2 + rs3);

    // pack P(kt) -> per-wave LDS (packed cvt, 8B stores)
    #pragma unroll
    for (int nf = 0; nf < 4; ++nf) {
      unsigned int w0 = cvtpk_bf16(s[nf][0], s[nf][1]);
      unsigned int w1 = cvtpk_bf16(s[nf][2], s[nf][3]);
      uint2 pr; pr.x = w0; pr.y = w1;
      *(uint2*)(pbase + ((nf * 32 + hi * 8) ^ pswz)) = pr;
    }
  }

  // final PV(nkt-1): P per-wave (in-wave lgkm ordering), V in regs
  // (compiler inserts the vmcnt wait before first use) -> no barrier needed.
  {
    #pragma unroll
    for (int ks2 = 0; ks2 < 2; ++ks2) {
      int kb = ks2 * 64 + hi * 16;
      bf16x8 pf = *(const bf16x8*)(Pw + lo * 128 + (kb ^ pswz));
      __builtin_amdgcn_s_setprio(1);
      #pragma unroll
      for (int df = 0; df < 4; ++df)
        Oacc[df] = __builtin_amdgcn_mfma_f32_16x16x32_bf16(vreg[ks2 * 4 + df], pf, Oacc[df], 0, 0, 0);
      __builtin_amdgcn_s_setprio(0);
    }
  }

  // reduce lrun partials across hi-groups, then finalize with 8B stores
  lrun += __shfl_xor(lrun, 16, 64);
  lrun += __shfl_xor(lrun, 32, 64);
  float inv = 1.0f / lrun;
  int t = q0 + wid * 16 + lo;
  size_t rowbase = ((size_t)(b * TSEQ + t)) * DIMSZ + h * 64;
  #pragma unroll
  for (int df = 0; df < 4; ++df) {
    bf16x4 o;
    #pragma unroll
    for (int r = 0; r < 4; ++r) o[r] = (short)f2bf(Oacc[df][r] * inv);
    *(bf16x4*)(Orow + rowbase + df * 16 + hi * 4) = o;
  }
}

// ---------------------------------------------------------------------------
extern "C" void kernel_launch(void* const* d_in, const int* in_sizes, int n_in,
                              void* d_out, int out_size, void* d_ws, size_t ws_size,
                              hipStream_t stream) {
  (void)in_sizes; (void)n_in; (void)out_size; (void)ws_size;
  const float* x     = (const float*)d_in[0];
  const float* ln_g  = (const float*)d_in[2];
  const float* ln_b  = (const float*)d_in[3];
  const float* w_qkv = (const float*)d_in[4];
  const float* qA    = (const float*)d_in[5];
  const float* qB    = (const float*)d_in[6];
  const float* kA    = (const float*)d_in[7];
  const float* kB    = (const float*)d_in[8];
  const float* vA    = (const float*)d_in[9];
  const float* vB    = (const float*)d_in[10];
  const float* w_out = (const float*)d_in[11];
  const float* b_out = (const float*)d_in[12];
  const float* outA  = (const float*)d_in[13];
  const float* outB  = (const float*)d_in[14];

  char* ws = (char*)d_ws;
  unsigned short* xn    = (unsigned short*)(ws);             // 8388608 B
  unsigned short* WqkvT = (unsigned short*)(ws + 8388608);   // 6291456 B
  unsigned short* WoutT = (unsigned short*)(ws + 14680064);  // 2097152 B
  float*          WA    = (float*)(ws + 16777216);           // 65536 B
  float*          beff  = (float*)(ws + 16842752);           // 4096 B
  unsigned short* Qb    = (unsigned short*)(ws + 16846848);  // 8388608 B
  unsigned short* Kb    = (unsigned short*)(ws + 25235456);  // 8388608 B
  unsigned short* Vtb   = (unsigned short*)(ws + 33624064);  // 8388608 B
  unsigned short* Orow  = xn;    // alias: xn dead after GEMM0
  float* outp = (float*)d_out;

  prep_kernel<<<MTOK + 257 + 768, 256, 0, stream>>>(x, ln_g, ln_b, w_out, outA,
      b_out, outB, w_qkv, qA, qB, kA, kB, vA, vB, xn, WA, beff, WqkvT);
  gemm_kernel<0><<<1024, 256, 0, stream>>>(xn, WqkvT, DIMSZ, Qb, Kb, Vtb,
      nullptr, nullptr, w_out, WA, outB, WoutT);
  attn_kernel<<<dim3(32, 32), 256, 0, stream>>>(Qb, Kb, Vtb, Orow);
  gemm_kernel<1><<<256, 256, 0, stream>>>(Orow, WoutT, DIMSZ, nullptr, nullptr,
      nullptr, beff, outp, nullptr, nullptr, nullptr, nullptr);
}

// Round 14
// 126.701 us; speedup vs baseline: 1.3319x; 1.2604x over previous
//
#include <hip/hip_runtime.h>

// ---------------------------------------------------------------------------
// AttentionWithLoRA, 4-kernel chain:
//   prep  (LN + WA=w_out@outA + beff + WqkvT fold z0-2)
//   gemm0 (QKV GEMM + WoutT fold tail)
//   attn  (R11-best flash attention: K/V staged, deferred-PV)
//   gemm1 (out-proj + bias, 128x64 tiles -> 2 blocks/CU)
// ---------------------------------------------------------------------------

#define DIMSZ 1024
#define TSEQ  2048
#define MTOK  4096   // B*T rows

typedef __attribute__((ext_vector_type(8))) short bf16x8;
typedef __attribute__((ext_vector_type(4))) short bf16x4;
typedef __attribute__((ext_vector_type(4))) float f32x4;

__device__ __forceinline__ unsigned short f2bf(float f) {
  unsigned int u = __float_as_uint(f);
  u += 0x7fffu + ((u >> 16) & 1u);   // round-nearest-even
  return (unsigned short)(u >> 16);
}
__device__ __forceinline__ float bf2f(unsigned short s) {
  return __uint_as_float(((unsigned int)s) << 16);
}
__device__ __forceinline__ unsigned int cvtpk_bf16(float a, float b) {
  unsigned int d;
  asm("v_cvt_pk_bf16_f32 %0, %1, %2" : "=v"(d) : "v"(a), "v"(b));
  return d;
}
__device__ __forceinline__ void gload16(const void* g, void* l) {
  __builtin_amdgcn_global_load_lds((const __attribute__((address_space(1))) void*)g,
                                   (__attribute__((address_space(3))) void*)l, 16, 0, 0);
}

// ---------------------------------------------------------------------------
// prep: blocks 0..4095 LayerNorm; 4096..4351 WA=w_out@outA (4 rows/blk);
// 4352: beff; 4353..5120: WqkvT fold (z = (bid-4353)>>8, 16x16 64-blocks).
// ---------------------------------------------------------------------------
__global__ __launch_bounds__(256) void prep_kernel(const float* __restrict__ x,
    const float* __restrict__ g, const float* __restrict__ bln,
    const float* __restrict__ w_out, const float* __restrict__ outA,
    const float* __restrict__ b_out, const float* __restrict__ outB,
    const float* __restrict__ w_qkv,
    const float* __restrict__ qA, const float* __restrict__ qB,
    const float* __restrict__ kA, const float* __restrict__ kB,
    const float* __restrict__ vA, const float* __restrict__ vB,
    unsigned short* __restrict__ xn, float* __restrict__ WA,
    float* __restrict__ beff, unsigned short* __restrict__ WqkvT) {
  __shared__ float red[8];
  __shared__ float sh[4][16];
  __shared__ float tt[16];
  int bid = blockIdx.x;
  int tid = threadIdx.x, wid = tid >> 6, lane = tid & 63;
  if (bid < MTOK) {
    int row = bid;
    const float4* xr = (const float4*)(x + (size_t)row * DIMSZ);
    float4 v = xr[tid];
    float s  = v.x + v.y + v.z + v.w;
    float s2 = v.x*v.x + v.y*v.y + v.z*v.z + v.w*v.w;
    #pragma unroll
    for (int off = 32; off > 0; off >>= 1) {
      s  += __shfl_xor(s, off, 64);
      s2 += __shfl_xor(s2, off, 64);
    }
    if (lane == 0) { red[wid] = s; red[wid + 4] = s2; }
    __syncthreads();
    s  = red[0] + red[1] + red[2] + red[3];
    s2 = red[4] + red[5] + red[6] + red[7];
    float mu  = s * (1.0f / DIMSZ);
    float var = s2 * (1.0f / DIMSZ) - mu * mu;
    float rstd = rsqrtf(var + 1e-5f);
    float4 gg = ((const float4*)g)[tid];
    float4 bb = ((const float4*)bln)[tid];
    ushort4 o;
    o.x = f2bf((v.x - mu) * rstd * gg.x + bb.x);
    o.y = f2bf((v.y - mu) * rstd * gg.y + bb.y);
    o.z = f2bf((v.z - mu) * rstd * gg.z + bb.z);
    o.w = f2bf((v.w - mu) * rstd * gg.w + bb.w);
    ((ushort4*)(xn + (size_t)row * DIMSZ))[tid] = o;
  } else if (bid < MTOK + 256) {
    int k = (bid - MTOK) * 4 + wid;
    float a[16];
    #pragma unroll
    for (int r = 0; r < 16; ++r) a[r] = 0.f;
    for (int c = lane; c < DIMSZ; c += 64) {
      float w = w_out[(size_t)k * DIMSZ + c];
      const float* ap = outA + (size_t)c * 16;
      #pragma unroll
      for (int r = 0; r < 16; ++r) a[r] += w * ap[r];
    }
    #pragma unroll
    for (int r = 0; r < 16; ++r) {
      #pragma unroll
      for (int off = 32; off > 0; off >>= 1) a[r] += __shfl_xor(a[r], off, 64);
    }
    if (lane < 16) WA[k * 16 + lane] = a[lane];
  } else if (bid == MTOK + 256) {
    float a[16];
    #pragma unroll
    for (int r = 0; r < 16; ++r) a[r] = 0.f;
    for (int c = tid; c < DIMSZ; c += 256) {
      float bo = b_out[c];
      const float* ap = outA + (size_t)c * 16;
      #pragma unroll
      for (int r = 0; r < 16; ++r) a[r] += bo * ap[r];
    }
    #pragma unroll
    for (int r = 0; r < 16; ++r) {
      #pragma unroll
      for (int off = 32; off > 0; off >>= 1) a[r] += __shfl_xor(a[r], off, 64);
    }
    if (lane == 0) {
      #pragma unroll
      for (int r = 0; r < 16; ++r) sh[wid][r] = a[r];
    }
    __syncthreads();
    if (tid < 16) tt[tid] = sh[0][tid] + sh[1][tid] + sh[2][tid] + sh[3][tid];
    __syncthreads();
    for (int n = tid; n < DIMSZ; n += 256) {
      float l = 0.f;
      #pragma unroll
      for (int r = 0; r < 16; ++r) l += tt[r] * outB[(size_t)r * DIMSZ + n];
      beff[n] = b_out[n] + 0.5f * l;
    }
  } else {
    // WqkvT fold: Wt[n][k] = w_qkv[k][coff+n] + 0.5*sum_r A[k][r]*Bf[r][n]
    __shared__ float Bsf[16][64];
    __shared__ unsigned short Ts[64][72];
    int fid = bid - (MTOK + 257);            // 0..767
    int z = fid >> 8, rem = fid & 255;
    int n0 = (rem & 15) * 64, k0 = (rem >> 4) * 64;
    const float *A, *Bf;
    unsigned short* Wt;
    if (z == 0)      { A = qA; Bf = qB; Wt = WqkvT; }
    else if (z == 1) { A = kA; Bf = kB; Wt = WqkvT + 1048576; }
    else             { A = vA; Bf = vB; Wt = WqkvT + 2097152; }
    int coff = z << 10;
    int tx = tid & 63, ty = tid >> 6;
    for (int r = ty; r < 16; r += 4) Bsf[r][tx] = Bf[(size_t)r * DIMSZ + n0 + tx];
    __syncthreads();
    for (int k = ty; k < 64; k += 4) {
      int kk = k0 + k;
      float w = w_qkv[(size_t)kk * 3072 + coff + n0 + tx];
      const float* Ar = A + (size_t)kk * 16;
      float lora = 0.f;
      #pragma unroll
      for (int r = 0; r < 16; ++r) lora += Ar[r] * Bsf[r][tx];
      Ts[tx][k] = f2bf(w + 0.5f * lora);
    }
    __syncthreads();
    for (int n = ty; n < 64; n += 4)
      Wt[(size_t)(n0 + n) * DIMSZ + k0 + tx] = Ts[n][tx];
  }
}

// ---------------------------------------------------------------------------
// GEMM0: C = A[M][K] * Bt[N][K]^T, 128x128 tile, BK=64, swapped-operand acc.
// blocks 0..767 = QKV GEMM (XCD swizzle); 768..1023 = WoutT fold tail.
// ---------------------------------------------------------------------------
__global__ __launch_bounds__(256) void gemm0_kernel(
    const unsigned short* __restrict__ Abf, const unsigned short* __restrict__ Bt,
    unsigned short* __restrict__ Qo, unsigned short* __restrict__ Ko,
    unsigned short* __restrict__ Vto,
    const float* __restrict__ w_out, const float* __restrict__ WAf,
    const float* __restrict__ outB, unsigned short* __restrict__ WoutT) {
  __shared__ __align__(16) char As[128 * 64 * 2];
  __shared__ __align__(16) char Bs[128 * 64 * 2];
  int lin = blockIdx.x;
  int tid = threadIdx.x;
  if (lin >= 768) {
    // WoutT fold: Wt[n][k] = w_out[k][n] + 0.5*sum_r WA[k][r]*outB[r][n]
    float (*Bsf)[64] = (float(*)[64])As;
    unsigned short (*Ts)[72] = (unsigned short(*)[72])(As + 4096);
    int rem = lin - 768;
    int n0 = (rem & 15) * 64, k0 = (rem >> 4) * 64;
    int tx = tid & 63, ty = tid >> 6;
    for (int r = ty; r < 16; r += 4) Bsf[r][tx] = outB[(size_t)r * DIMSZ + n0 + tx];
    __syncthreads();
    for (int k = ty; k < 64; k += 4) {
      int kk = k0 + k;
      float w = w_out[(size_t)kk * DIMSZ + n0 + tx];
      const float* Ar = WAf + (size_t)kk * 16;
      float lora = 0.f;
      #pragma unroll
      for (int r = 0; r < 16; ++r) lora += Ar[r] * Bsf[r][tx];
      Ts[tx][k] = f2bf(w + 0.5f * lora);
    }
    __syncthreads();
    for (int n = ty; n < 64; n += 4)
      WoutT[(size_t)(n0 + n) * DIMSZ + k0 + tx] = Ts[n][tx];
    return;
  }
  int cpx = 768 >> 3;
  int swz = (lin & 7) * cpx + (lin >> 3);
  int bx = swz % 24;
  int by = swz / 24;
  int n0 = bx * 128;
  int m0 = by * 128;
  int wid = tid >> 6, lane = tid & 63;
  int wr = wid >> 1, wc = wid & 1;
  int hi = lane >> 4;
  f32x4 acc[4][4];   // [n][m]
  #pragma unroll
  for (int i = 0; i < 4; ++i)
    #pragma unroll
    for (int j = 0; j < 4; ++j) acc[i][j] = (f32x4){0.f, 0.f, 0.f, 0.f};

  const char* gA = (const char*)Abf;
  const char* gB = (const char*)Bt;
  for (int kt = 0; kt < 16; ++kt) {
    #pragma unroll
    for (int j = 0; j < 4; ++j) {
      int it = wid * 4 + j;
      int p = it * 1024 + lane * 16;
      int row = p >> 7, colb = p & 127;
      int L = colb ^ ((row & 7) << 4);
      gload16(gA + (size_t)(m0 + row) * 2048 + kt * 128 + L, As + it * 1024);
      gload16(gB + (size_t)(n0 + row) * 2048 + kt * 128 + L, Bs + it * 1024);
    }
    __syncthreads();
    #pragma unroll
    for (int ks = 0; ks < 2; ++ks) {
      int kb = ks * 64 + hi * 16;
      bf16x8 af[4], bfr[4];
      #pragma unroll
      for (int m = 0; m < 4; ++m) {
        int row = wr * 64 + m * 16 + (lane & 15);
        af[m] = *(const bf16x8*)(As + row * 128 + (kb ^ ((row & 7) << 4)));
      }
      #pragma unroll
      for (int n = 0; n < 4; ++n) {
        int row = wc * 64 + n * 16 + (lane & 15);
        bfr[n] = *(const bf16x8*)(Bs + row * 128 + (kb ^ ((row & 7) << 4)));
      }
      __builtin_amdgcn_s_setprio(1);
      #pragma unroll
      for (int n = 0; n < 4; ++n)
        #pragma unroll
        for (int m = 0; m < 4; ++m)
          acc[n][m] = __builtin_amdgcn_mfma_f32_16x16x32_bf16(bfr[n], af[m], acc[n][m], 0, 0, 0);
      __builtin_amdgcn_s_setprio(0);
    }
    __syncthreads();
  }

  int sec  = n0 >> 10;                  // 0=q 1=k 2=v (tile never straddles)
  int nloc = (n0 & 1023) + wc * 64;
  int h = nloc >> 6;                    // each wave covers exactly one head
  int mbase = m0 + wr * 64;
  #pragma unroll
  for (int m = 0; m < 4; ++m) {
    int gm = mbase + m * 16 + (lane & 15);
    int bb = gm >> 11, t = gm & 2047;
    #pragma unroll
    for (int n = 0; n < 4; ++n) {
      int dloc = n * 16 + hi * 4;
      if (sec == 2) {
        #pragma unroll
        for (int r = 0; r < 4; ++r)
          Vto[((size_t)((bb * 16 + h) * 64 + dloc + r)) * TSEQ + t] = f2bf(acc[n][m][r]);
      } else {
        bf16x4 o;
        #pragma unroll
        for (int r = 0; r < 4; ++r) o[r] = (short)f2bf(acc[n][m][r]);
        size_t idx = ((size_t)(bb * 16 + h) * TSEQ + t) * 64 + dloc;
        *(bf16x4*)((sec == 0 ? Qo : Ko) + idx) = o;
      }
    }
  }
}

// ---------------------------------------------------------------------------
// GEMM1: Cout[M][1024] f32 = A[M][K] * Bt[N][K]^T + bias. 128x64 tiles,
// grid 512 = 2 blocks/CU (overlap staging drains with MFMA across blocks).
// ---------------------------------------------------------------------------
__global__ __launch_bounds__(256) void gemm1_kernel(
    const unsigned short* __restrict__ Abf, const unsigned short* __restrict__ Bt,
    const float* __restrict__ bias, float* __restrict__ Cout) {
  __shared__ __align__(16) char As[128 * 64 * 2];   // 16 KB
  __shared__ __align__(16) char Bs[64 * 64 * 2];    // 8 KB
  int lin = blockIdx.x;                  // 0..511
  int swz = (lin & 7) * 64 + (lin >> 3); // XCD-chunked, bijective (512%8==0)
  int bx = swz & 15, by = swz >> 4;
  int n0 = bx * 64, m0 = by * 128;
  int tid = threadIdx.x;
  int wid = tid >> 6, lane = tid & 63;
  int wr = wid >> 1, wc = wid & 1;
  int hi = lane >> 4, lo = lane & 15;
  f32x4 acc[2][4];   // [n][m]
  #pragma unroll
  for (int i = 0; i < 2; ++i)
    #pragma unroll
    for (int j = 0; j < 4; ++j) acc[i][j] = (f32x4){0.f, 0.f, 0.f, 0.f};

  const char* gA = (const char*)Abf;
  const char* gB = (const char*)Bt;
  for (int kt = 0; kt < 16; ++kt) {
    // stage A (16 KB): 4 chunks/thread
    #pragma unroll
    for (int j = 0; j < 4; ++j) {
      int it = wid * 4 + j;
      int p = it * 1024 + lane * 16;
      int row = p >> 7, colb = p & 127;
      int L = colb ^ ((row & 7) << 4);
      gload16(gA + (size_t)(m0 + row) * 2048 + kt * 128 + L, As + it * 1024);
    }
    // stage B (8 KB): 2 chunks/thread
    {
      int p = tid * 16;
      int row = p >> 7, colb = p & 127;
      int L = colb ^ ((row & 7) << 4);
      gload16(gB + (size_t)(n0 + row) * 2048 + kt * 128 + L, Bs + p);
      int p2 = p + 4096;
      int row2 = p2 >> 7;
      int L2 = colb ^ ((row2 & 7) << 4);
      gload16(gB + (size_t)(n0 + row2) * 2048 + kt * 128 + L2, Bs + p2);
    }
    __syncthreads();
    #pragma unroll
    for (int ks = 0; ks < 2; ++ks) {
      int kb = ks * 64 + hi * 16;
      bf16x8 af[4], bfr[2];
      #pragma unroll
      for (int m = 0; m < 4; ++m) {
        int row = wr * 64 + m * 16 + lo;
        af[m] = *(const bf16x8*)(As + row * 128 + (kb ^ ((row & 7) << 4)));
      }
      #pragma unroll
      for (int n = 0; n < 2; ++n) {
        int row = wc * 32 + n * 16 + lo;
        bfr[n] = *(const bf16x8*)(Bs + row * 128 + (kb ^ ((row & 7) << 4)));
      }
      __builtin_amdgcn_s_setprio(1);
      #pragma unroll
      for (int n = 0; n < 2; ++n)
        #pragma unroll
        for (int m = 0; m < 4; ++m)
          acc[n][m] = __builtin_amdgcn_mfma_f32_16x16x32_bf16(bfr[n], af[m], acc[n][m], 0, 0, 0);
      __builtin_amdgcn_s_setprio(0);
    }
    __syncthreads();
  }

  int mbase = m0 + wr * 64;
  int nbase = n0 + wc * 32;
  #pragma unroll
  for (int m = 0; m < 4; ++m) {
    int t = mbase + m * 16 + lo;
    #pragma unroll
    for (int n = 0; n < 2; ++n) {
      int c = nbase + n * 16 + hi * 4;
      float4 bs = *(const float4*)(bias + c);
      float4 o;
      o.x = acc[n][m][0] + bs.x;
      o.y = acc[n][m][1] + bs.y;
      o.z = acc[n][m][2] + bs.z;
      o.w = acc[n][m][3] + bs.w;
      *(float4*)(Cout + (size_t)t * DIMSZ + c) = o;
    }
  }
}

// ---------------------------------------------------------------------------
// Flash attention (R11-best). QBLK=64 (4 waves x 16 q-rows), KVBLK=64.
// Deferred-PV: at iter kt, QK(kt) then PV(kt-1) (independent) overlap the
// softmax reduce; V staging shifted one iter later than K.
// Grid: x=bh(32), y=32: y<16 -> qt=31-y (heavy first), else qt=y-16.
// ---------------------------------------------------------------------------
__global__ __launch_bounds__(256, 4) void attn_kernel(
    const unsigned short* __restrict__ Qg, const unsigned short* __restrict__ Kg,
    const unsigned short* __restrict__ Vt, unsigned short* __restrict__ Orow) {
  __shared__ __align__(16) char KsB[2][64 * 128];   // [key][d]  16 KB
  __shared__ __align__(16) char VsB[2][64 * 128];   // [d][key]  16 KB
  __shared__ __align__(16) char Ps[4][16 * 128];    // per-wave P [q][key] 8 KB
  int bh = blockIdx.x;
  int y  = blockIdx.y;
  int qt = (y < 16) ? (31 - y) : (y - 16);          // heavy tiles dispatch first
  int b = bh >> 4, h = bh & 15;
  int tid = threadIdx.x, wid = tid >> 6, lane = tid & 63;
  int hi = lane >> 4, lo = lane & 15;
  const char* Qb = (const char*)(Qg + (size_t)bh * TSEQ * 64);
  const char* Kb = (const char*)(Kg + (size_t)bh * TSEQ * 64);
  const char* Vb = (const char*)(Vt + (size_t)bh * 64 * TSEQ);
  int q0 = qt * 64;

  // staging geometry: thread -> 2 K-rows + 2 V-rows (16B each, swizzled src)
  int srow = tid >> 3;                                   // 0..31
  int scol = ((tid & 7) << 4) ^ ((srow & 7) << 4);

  // Q B-frags with 0.125*log2e folded (exp2-domain softmax)
  const float qscale = 0.18033688f;
  bf16x8 qf[2];
  {
    int row = q0 + wid * 16 + lo;
    #pragma unroll
    for (int ks = 0; ks < 2; ++ks) {
      bf16x8 raw = *(const bf16x8*)(Qb + (size_t)row * 128 + ks * 64 + hi * 16);
      bf16x8 sc;
      #pragma unroll
      for (int i = 0; i < 8; ++i)
        sc[i] = (short)f2bf(bf2f((unsigned short)raw[i]) * qscale);
      qf[ks] = sc;
    }
  }

  f32x4 Oacc[4];                 // O^T: d = df*16 + hi*4 + r, q = lo
  #pragma unroll
  for (int df = 0; df < 4; ++df) Oacc[df] = (f32x4){0.f, 0.f, 0.f, 0.f};
  float mrun = -INFINITY, lrun = 0.f;   // lrun = per-lane partial (16 keys)

  char* Pw = Ps[wid];
  char* pbase = Pw + lo * 128;
  int pswz = (lo & 7) << 4;

  int nkt = ((qt >> 2) + 1) << 2;   // (frame+1) * 256/64

  // prologue: stage K(0), V(0) into buffer 0
  {
    const char* ksrc = Kb + (size_t)srow * 128 + scol;
    gload16(ksrc,               KsB[0] + tid * 16);
    gload16(ksrc + 32 * 128,    KsB[0] + tid * 16 + 4096);
    const char* vsrc = Vb + (size_t)srow * (TSEQ * 2) + scol;
    gload16(vsrc,               VsB[0] + tid * 16);
    gload16(vsrc + 32 * (TSEQ * 2), VsB[0] + tid * 16 + 4096);
  }

  for (int kt = 0; kt < nkt; ++kt) {
    __syncthreads();   // waits K(kt) staged + V(kt-1) staged + prior-iter reads
    if (kt + 1 < nkt) {   // stage K(kt+1)
      int k0n = (kt + 1) << 6;
      char* kd = KsB[(kt + 1) & 1];
      const char* ksrc = Kb + (size_t)(k0n + srow) * 128 + scol;
      gload16(ksrc,            kd + tid * 16);
      gload16(ksrc + 32 * 128, kd + tid * 16 + 4096);
    }
    if (kt) {             // stage V(kt) (consumed by PV(kt) at iter kt+1)
      char* vd = VsB[kt & 1];
      const char* vsrc = Vb + (size_t)srow * (TSEQ * 2) + (kt << 7) + scol;
      gload16(vsrc,                   vd + tid * 16);
      gload16(vsrc + 32 * (TSEQ * 2), vd + tid * 16 + 4096);
    }
    const char* Kbuf = KsB[kt & 1];

    // S^T = K Q^T : s[nf], key = nf*16 + hi*4 + r, q = lo
    f32x4 s[4];
    #pragma unroll
    for (int nf = 0; nf < 4; ++nf) s[nf] = (f32x4){0.f, 0.f, 0.f, 0.f};
    #pragma unroll
    for (int ks = 0; ks < 2; ++ks) {
      int kb = ks * 64 + hi * 16;
      bf16x8 kf[4];
      #pragma unroll
      for (int nf = 0; nf < 4; ++nf) {
        int row = nf * 16 + lo;
        kf[nf] = *(const bf16x8*)(Kbuf + row * 128 + (kb ^ ((row & 7) << 4)));
      }
      __builtin_amdgcn_s_setprio(1);
      #pragma unroll
      for (int nf = 0; nf < 4; ++nf)
        s[nf] = __builtin_amdgcn_mfma_f32_16x16x32_bf16(kf[nf], qf[ks], s[nf], 0, 0, 0);
      __builtin_amdgcn_s_setprio(0);
    }

    // PV(kt-1): independent of QK(kt) -> overlaps the max-reduce below
    if (kt) {
      const char* Vbuf = VsB[(kt - 1) & 1];
      #pragma unroll
      for (int ks2 = 0; ks2 < 2; ++ks2) {
        int kb = ks2 * 64 + hi * 16;
        bf16x8 pf = *(const bf16x8*)(Pw + lo * 128 + (kb ^ pswz));
        bf16x8 vf[4];
        #pragma unroll
        for (int df = 0; df < 4; ++df) {
          int row = df * 16 + lo;
          vf[df] = *(const bf16x8*)(Vbuf + row * 128 + (kb ^ ((row & 7) << 4)));
        }
        __builtin_amdgcn_s_setprio(1);
        #pragma unroll
        for (int df = 0; df < 4; ++df)
          Oacc[df] = __builtin_amdgcn_mfma_f32_16x16x32_bf16(vf[df], pf, Oacc[df], 0, 0, 0);
        __builtin_amdgcn_s_setprio(0);
      }
    }

    // max over 16 scores (tree), then across hi-groups
    float a0 = fmaxf(fmaxf(s[0][0], s[0][1]), fmaxf(s[0][2], s[0][3]));
    float a1 = fmaxf(fmaxf(s[1][0], s[1][1]), fmaxf(s[1][2], s[1][3]));
    float a2 = fmaxf(fmaxf(s[2][0], s[2][1]), fmaxf(s[2][2], s[2][3]));
    float a3 = fmaxf(fmaxf(s[3][0], s[3][1]), fmaxf(s[3][2], s[3][3]));
    float mx = fmaxf(fmaxf(a0, a1), fmaxf(a2, a3));
    mx = fmaxf(mx, __shfl_xor(mx, 16, 64));
    mx = fmaxf(mx, __shfl_xor(mx, 32, 64));

    // defer-max (THR=8 in log2 units): skip O-rescale when max barely grows
    if (!__all(mx <= mrun + 8.0f)) {
      float mn = fmaxf(mrun, mx);
      float al = exp2f(mrun - mn);
      mrun = mn;
      lrun *= al;
      #pragma unroll
      for (int df = 0; df < 4; ++df)
        #pragma unroll
        for (int r = 0; r < 4; ++r) Oacc[df][r] *= al;
    }

    // exp2 + per-lane partial row-sum (no shuffles here)
    float rs0 = 0.f, rs1 = 0.f, rs2 = 0.f, rs3 = 0.f;
    #pragma unroll
    for (int nf = 0; nf < 4; ++nf) {
      float p0 = exp2f(s[nf][0] - mrun);
      float p1 = exp2f(s[nf][1] - mrun);
      float p2 = exp2f(s[nf][2] - mrun);
      float p3 = exp2f(s[nf][3] - mrun);
      s[nf][0] = p0; s[nf][1] = p1; s[nf][2] = p2; s[nf][3] = p3;
      rs0 += p0; rs1 += p1; rs2 += p2; rs3 += p3;
    }
    lrun += (rs0 + rs1) + (rs2 + rs3);

    // pack P(kt) -> per-wave LDS (packed cvt, 8B stores)
    #pragma unroll
    for (int nf = 0; nf < 4; ++nf) {
      unsigned int w0 = cvtpk_bf16(s[nf][0], s[nf][1]);
      unsigned int w1 = cvtpk_bf16(s[nf][2], s[nf][3]);
      uint2 pr; pr.x = w0; pr.y = w1;
      *(uint2*)(pbase + ((nf * 32 + hi * 8) ^ pswz)) = pr;
    }
  }

  // final PV(nkt-1): V(nkt-1) staged at iter nkt-1 -> barrier, then consume
  __syncthreads();
  {
    const char* Vbuf = VsB[(nkt - 1) & 1];
    #pragma unroll
    for (int ks2 = 0; ks2 < 2; ++ks2) {
      int kb = ks2 * 64 + hi * 16;
      bf16x8 pf = *(const bf16x8*)(Pw + lo * 128 + (kb ^ pswz));
      bf16x8 vf[4];
      #pragma unroll
      for (int df = 0; df < 4; ++df) {
        int row = df * 16 + lo;
        vf[df] = *(const bf16x8*)(Vbuf + row * 128 + (kb ^ ((row & 7) << 4)));
      }
      __builtin_amdgcn_s_setprio(1);
      #pragma unroll
      for (int df = 0; df < 4; ++df)
        Oacc[df] = __builtin_amdgcn_mfma_f32_16x16x32_bf16(vf[df], pf, Oacc[df], 0, 0, 0);
      __builtin_amdgcn_s_setprio(0);
    }
  }

  // reduce lrun partials across hi-groups, then finalize with 8B stores
  lrun += __shfl_xor(lrun, 16, 64);
  lrun += __shfl_xor(lrun, 32, 64);
  float inv = 1.0f / lrun;
  int t = q0 + wid * 16 + lo;
  size_t rowbase = ((size_t)(b * TSEQ + t)) * DIMSZ + h * 64;
  #pragma unroll
  for (int df = 0; df < 4; ++df) {
    bf16x4 o;
    #pragma unroll
    for (int r = 0; r < 4; ++r) o[r] = (short)f2bf(Oacc[df][r] * inv);
    *(bf16x4*)(Orow + rowbase + df * 16 + hi * 4) = o;
  }
}

// ---------------------------------------------------------------------------
extern "C" void kernel_launch(void* const* d_in, const int* in_sizes, int n_in,
                              void* d_out, int out_size, void* d_ws, size_t ws_size,
                              hipStream_t stream) {
  (void)in_sizes; (void)n_in; (void)out_size; (void)ws_size;
  const float* x     = (const float*)d_in[0];
  const float* ln_g  = (const float*)d_in[2];
  const float* ln_b  = (const float*)d_in[3];
  const float* w_qkv = (const float*)d_in[4];
  const float* qA    = (const float*)d_in[5];
  const float* qB    = (const float*)d_in[6];
  const float* kA    = (const float*)d_in[7];
  const float* kB    = (const float*)d_in[8];
  const float* vA    = (const float*)d_in[9];
  const float* vB    = (const float*)d_in[10];
  const float* w_out = (const float*)d_in[11];
  const float* b_out = (const float*)d_in[12];
  const float* outA  = (const float*)d_in[13];
  const float* outB  = (const float*)d_in[14];

  char* ws = (char*)d_ws;
  unsigned short* xn    = (unsigned short*)(ws);             // 8388608 B
  unsigned short* WqkvT = (unsigned short*)(ws + 8388608);   // 6291456 B
  unsigned short* WoutT = (unsigned short*)(ws + 14680064);  // 2097152 B
  float*          WA    = (float*)(ws + 16777216);           // 65536 B
  float*          beff  = (float*)(ws + 16842752);           // 4096 B
  unsigned short* Qb    = (unsigned short*)(ws + 16846848);  // 8388608 B
  unsigned short* Kb    = (unsigned short*)(ws + 25235456);  // 8388608 B
  unsigned short* Vtb   = (unsigned short*)(ws + 33624064);  // 8388608 B
  unsigned short* Orow  = xn;    // alias: xn dead after GEMM0
  float* outp = (float*)d_out;

  prep_kernel<<<MTOK + 257 + 768, 256, 0, stream>>>(x, ln_g, ln_b, w_out, outA,
      b_out, outB, w_qkv, qA, qB, kA, kB, vA, vB, xn, WA, beff, WqkvT);
  gemm0_kernel<<<1024, 256, 0, stream>>>(xn, WqkvT, Qb, Kb, Vtb,
      w_out, WA, outB, WoutT);
  attn_kernel<<<dim3(32, 32), 256, 0, stream>>>(Qb, Kb, Vtb, Orow);
  gemm1_kernel<<<512, 256, 0, stream>>>(Orow, WoutT, beff, outp);
}